// Round 2
// baseline (1362.233 us; speedup 1.0000x reference)
//
#include <hip/hip_runtime.h>

#define B_TOT 2304
#define CHAN 22
#define TP 250
#define KW 13
#define ST 64
#define RANK 32
#define FE_PER 528
#define FE_TOTAL (B_TOT * FE_PER)   // 1216512
#define FEAT 4752
#define NC 4
#define NBS 256

// ---------------- downsample: mean over groups of 4 ----------------
__global__ __launch_bounds__(256) void ds_kernel(const float* __restrict__ x,
                                                 float* __restrict__ xds, int n) {
  int idx = blockIdx.x * 256 + threadIdx.x;
  if (idx < n) {
    float4 v = reinterpret_cast<const float4*>(x)[idx];
    xds[idx] = (v.x + v.y + v.z + v.w) * 0.25f;
  }
}

// -------- conv + BN + center + cov + bimap, one block per (b, m) --------
__global__ __launch_bounds__(256) void ccb_kernel(
    const float* __restrict__ xds, const float* __restrict__ conv_w,
    const float* __restrict__ conv_b, const float* __restrict__ bn_gamma,
    const float* __restrict__ bn_beta, const float* __restrict__ bn_mean,
    const float* __restrict__ bn_var, const float* __restrict__ bimap_w,
    float* __restrict__ ybuf) {
  const int b = blockIdx.x;
  const int m = blockIdx.y;
  const int off = (m == 0) ? 0 : (m == 1) ? 84 : 167;
  const int l = (m == 0) ? 84 : 83;
  const int tid = threadIdx.x;

  __shared__ union {
    float xseg[CHAN][96];   // input window [off-6, off+90)
    float t1[RANK][ST];     // W*C after cov is done (xseg dead by then)
  } u;
  __shared__ float S[ST][85];     // conv+bn output, then centered
  __shared__ float covm[ST][65];  // covariance
  __shared__ float rowmean[ST];
  __shared__ float trace_s;

  // ---- stage input window ----
  const float* xb = xds + (size_t)b * CHAN * TP;
  for (int i = tid; i < CHAN * 96; i += 256) {
    int c = i / 96, tt = i - c * 96;
    int gt = off - 6 + tt;
    u.xseg[c][tt] = (gt >= 0 && gt < TP) ? xb[c * TP + gt] : 0.0f;
  }
  __syncthreads();

  // ---- conv + bias + BN -> S[o][t] ----
  {
    int og = tid >> 4, tg = tid & 15;  // 16 o-groups x 16 t-groups
    int o0 = og * 4, t0 = tg * 6;
    if (t0 < l) {
      float acc[4][6];
#pragma unroll
      for (int a = 0; a < 4; a++)
#pragma unroll
        for (int t = 0; t < 6; t++) acc[a][t] = 0.f;
      for (int c = 0; c < CHAN; c++) {
        float win[18];
#pragma unroll
        for (int j = 0; j < 18; j++) win[j] = u.xseg[c][t0 + j];
        const float* wc0 = conv_w + (o0 + 0) * CHAN * KW + c * KW;
        const float* wc1 = conv_w + (o0 + 1) * CHAN * KW + c * KW;
        const float* wc2 = conv_w + (o0 + 2) * CHAN * KW + c * KW;
        const float* wc3 = conv_w + (o0 + 3) * CHAN * KW + c * KW;
#pragma unroll
        for (int k = 0; k < KW; k++) {
          float w0 = wc0[k], w1 = wc1[k], w2 = wc2[k], w3 = wc3[k];
#pragma unroll
          for (int t = 0; t < 6; t++) {
            float xv = win[k + t];
            acc[0][t] += w0 * xv;
            acc[1][t] += w1 * xv;
            acc[2][t] += w2 * xv;
            acc[3][t] += w3 * xv;
          }
        }
      }
#pragma unroll
      for (int a = 0; a < 4; a++) {
        int o = o0 + a;
        float inv = bn_gamma[o] * rsqrtf(bn_var[o] + 1e-5f);
        float shift = bn_beta[o] - bn_mean[o] * inv;
#pragma unroll
        for (int t = 0; t < 6; t++) {
          int tt = t0 + t;
          if (tt < l) S[o][tt] = (acc[a][t] + conv_b[o]) * inv + shift;
        }
      }
    }
  }
  __syncthreads();

  // ---- per-row mean over time, then center ----
  {
    int row = tid >> 2, part = tid & 3;
    float ssum = 0.f;
    for (int t = part; t < l; t += 4) ssum += S[row][t];
    ssum += __shfl_xor(ssum, 1);
    ssum += __shfl_xor(ssum, 2);
    if (part == 0) rowmean[row] = ssum / (float)l;
  }
  __syncthreads();
  for (int i = tid; i < ST * 84; i += 256) {
    int o = i / 84, t = i - o * 84;
    if (t < l) S[o][t] -= rowmean[o];
  }
  __syncthreads();

  // ---- covariance: 4x4 register tile per thread ----
  {
    int iy = tid >> 4, jx = tid & 15;
    int i0 = iy * 4, j0 = jx * 4;
    float acc[4][4];
#pragma unroll
    for (int a = 0; a < 4; a++)
#pragma unroll
      for (int c = 0; c < 4; c++) acc[a][c] = 0.f;
    for (int t = 0; t < l; t++) {
      float av[4], bv[4];
#pragma unroll
      for (int a = 0; a < 4; a++) av[a] = S[i0 + a][t];
#pragma unroll
      for (int a = 0; a < 4; a++) bv[a] = S[j0 + a][t];
#pragma unroll
      for (int a = 0; a < 4; a++)
#pragma unroll
        for (int c = 0; c < 4; c++) acc[a][c] += av[a] * bv[c];
    }
    float rn = 1.0f / (float)(l - 1);
#pragma unroll
    for (int a = 0; a < 4; a++)
#pragma unroll
      for (int c = 0; c < 4; c++) covm[i0 + a][j0 + c] = acc[a][c] * rn;
  }
  __syncthreads();

  // ---- trace normalize + eps*I ----
  if (tid < 64) {
    float v = covm[tid][tid];
#pragma unroll
    for (int d = 32; d >= 1; d >>= 1) v += __shfl_xor(v, d);
    if (tid == 0) trace_s = v;
  }
  __syncthreads();
  {
    float rs = 1.0f / trace_s;
    for (int i = tid; i < ST * ST; i += 256) {
      int r = i >> 6, c = i & 63;
      float v = covm[r][c] * rs;
      if (r == c) v += 1e-5f;
      covm[r][c] = v;
    }
  }
  __syncthreads();

  // ---- t1 = W * C  (32x64) ----
  {
    int o = tid >> 3, jg = tid & 7;
    int j0 = jg * 8;
    float acc[8];
#pragma unroll
    for (int a = 0; a < 8; a++) acc[a] = 0.f;
    const float* wrow = bimap_w + o * ST;
    for (int i = 0; i < ST; i++) {
      float wv = wrow[i];
#pragma unroll
      for (int a = 0; a < 8; a++) acc[a] += wv * covm[i][j0 + a];
    }
#pragma unroll
    for (int a = 0; a < 8; a++) u.t1[o][j0 + a] = acc[a];
  }
  __syncthreads();

  // ---- y_m = t1 * W^T (32x32), scaled by 1/3, to ws ----
  {
    int o = tid >> 3, pg = tid & 7;
    int p0 = pg * 4;
    float acc[4] = {0.f, 0.f, 0.f, 0.f};
    for (int j = 0; j < ST; j++) {
      float tv = u.t1[o][j];
#pragma unroll
      for (int a = 0; a < 4; a++) acc[a] += tv * bimap_w[(p0 + a) * ST + j];
    }
    float* yb = ybuf + (size_t)(b * 3 + m) * RANK * RANK;
#pragma unroll
    for (int a = 0; a < 4; a++) yb[o * RANK + p0 + a] = acc[a] * (1.0f / 3.0f);
  }
}

// -------- batched 32x32 symmetric eigh (cyclic Jacobi) + logm + fe --------
__global__ __launch_bounds__(256) void eig_kernel(const float* __restrict__ ybuf,
                                                  float* __restrict__ feout) {
  int b = blockIdx.x;
  int tid = threadIdx.x;
  __shared__ float A[32][33];
  __shared__ float V[32][33];
  __shared__ float cs[16], sn[16];
  __shared__ int pp[16], qq[16];
  __shared__ float lam[32];
  __shared__ float redo[4], redf[4];

  const float* yb = ybuf + (size_t)b * 3 * 1024;
  for (int i = tid; i < 1024; i += 256) {
    int r = i >> 5, c = i & 31;
    float v = yb[i] + yb[1024 + i] + yb[2048 + i];
    int it = c * 32 + r;
    float vt = yb[it] + yb[1024 + it] + yb[2048 + it];
    A[r][c] = 0.5f * (v + vt);
    V[r][c] = (r == c) ? 1.0f : 0.0f;
  }

  for (int sw = 0; sw < 12; sw++) {
    __syncthreads();
    // off-diagonal norm early exit
    float loc = 0.f, frol = 0.f;
    for (int i = tid; i < 1024; i += 256) {
      int r = i >> 5, c = i & 31;
      float v = A[r][c];
      frol += v * v;
      if (r != c) loc += v * v;
    }
#pragma unroll
    for (int d = 32; d >= 1; d >>= 1) {
      loc += __shfl_xor(loc, d);
      frol += __shfl_xor(frol, d);
    }
    if ((tid & 63) == 0) { redo[tid >> 6] = loc; redf[tid >> 6] = frol; }
    __syncthreads();
    float offn = redo[0] + redo[1] + redo[2] + redo[3];
    float fro2 = redf[0] + redf[1] + redf[2] + redf[3];
    if (offn <= 1e-13f * fro2) break;

    for (int rr = 0; rr < 31; rr++) {
      __syncthreads();
      if (tid < 16) {
        int p, q;
        if (tid == 0) { p = 31; q = rr; }
        else { p = (rr + tid) % 31; q = (rr + 31 - tid) % 31; }
        float app = A[p][p], aqq = A[q][q], apq = A[p][q];
        float c, s;
        if (fabsf(apq) < 1e-30f) { c = 1.f; s = 0.f; }
        else {
          float tau = (aqq - app) / (2.f * apq);
          float t = copysignf(1.f, tau) / (fabsf(tau) + sqrtf(1.f + tau * tau));
          c = rsqrtf(1.f + t * t);
          s = t * c;
        }
        cs[tid] = c; sn[tid] = s; pp[tid] = p; qq[tid] = q;
      }
      __syncthreads();
      // row phase: A <- J^T A
      for (int it = tid; it < 512; it += 256) {
        int k = it >> 5, col = it & 31;
        int p = pp[k], q = qq[k];
        float c = cs[k], s = sn[k];
        float ap = A[p][col], aq = A[q][col];
        A[p][col] = c * ap - s * aq;
        A[q][col] = s * ap + c * aq;
      }
      __syncthreads();
      // col phase: A <- A J,  V <- V J
      for (int it = tid; it < 1024; it += 256) {
        int k = (it >> 5) & 15;
        int row = it & 31;
        int p = pp[k], q = qq[k];
        float c = cs[k], s = sn[k];
        if (it < 512) {
          float ap = A[row][p], aq = A[row][q];
          A[row][p] = c * ap - s * aq;
          A[row][q] = s * ap + c * aq;
        } else {
          float vp = V[row][p], vq = V[row][q];
          V[row][p] = c * vp - s * vq;
          V[row][q] = s * vp + c * vq;
        }
      }
    }
  }
  __syncthreads();

  if (tid < 32) lam[tid] = logf(fmaxf(A[tid][tid], 1e-4f));
  __syncthreads();

  // fe = triu(V diag(lam) V^T) with sqrt(2) off-diag scaling
  for (int idx = tid; idx < FE_PER; idx += 256) {
    int i = 0, rem = idx;
    while (rem >= 32 - i) { rem -= 32 - i; i++; }
    int j = i + rem;
    float acc = 0.f;
#pragma unroll
    for (int k = 0; k < 32; k++) acc += V[i][k] * lam[k] * V[j][k];
    float scalef = (i == j) ? 1.0f : 1.4142135623730951f;
    feout[(size_t)b * FE_PER + idx] = acc * scalef;
  }
}

// ---------------- logits = fe @ W^T + b ----------------
__global__ __launch_bounds__(256) void logits_kernel(const float* __restrict__ fe,
                                                     const float* __restrict__ lw,
                                                     const float* __restrict__ lb,
                                                     float* __restrict__ outp) {
  int bs = blockIdx.x, tid = threadIdx.x;
  const float* f = fe + (size_t)bs * FEAT;
  float acc[NC] = {0.f, 0.f, 0.f, 0.f};
  for (int i = tid; i < FEAT; i += 256) {
    float v = f[i];
#pragma unroll
    for (int c = 0; c < NC; c++) acc[c] += v * lw[c * FEAT + i];
  }
  __shared__ float partial[4][NC];
#pragma unroll
  for (int c = 0; c < NC; c++) {
    float v = acc[c];
#pragma unroll
    for (int d = 32; d >= 1; d >>= 1) v += __shfl_xor(v, d);
    acc[c] = v;
  }
  if ((tid & 63) == 0) {
    int wave = tid >> 6;
#pragma unroll
    for (int c = 0; c < NC; c++) partial[wave][c] = acc[c];
  }
  __syncthreads();
  if (tid == 0) {
#pragma unroll
    for (int c = 0; c < NC; c++) {
      float sum = partial[0][c] + partial[1][c] + partial[2][c] + partial[3][c];
      outp[bs * NC + c] = sum + lb[c];
    }
  }
}

extern "C" void kernel_launch(void* const* d_in, const int* in_sizes, int n_in,
                              void* d_out, int out_size, void* d_ws, size_t ws_size,
                              hipStream_t stream) {
  const float* x        = (const float*)d_in[0];
  const float* conv_w   = (const float*)d_in[1];
  const float* conv_b   = (const float*)d_in[2];
  const float* bn_gamma = (const float*)d_in[3];
  const float* bn_beta  = (const float*)d_in[4];
  const float* bn_mean  = (const float*)d_in[5];
  const float* bn_var   = (const float*)d_in[6];
  const float* bimap_w  = (const float*)d_in[7];
  const float* linear_w = (const float*)d_in[8];
  const float* linear_b = (const float*)d_in[9];
  float* out = (float*)d_out;

  float* xds  = (float*)d_ws;          // 12,672,000 floats (50.7 MB)
  float* ybuf = xds + 12672000;        // 2304*3*1024 = 7,077,888 floats (28.3 MB)

  int n = B_TOT * CHAN * TP;
  ds_kernel<<<(n + 255) / 256, 256, 0, stream>>>(x, xds, n);

  dim3 g2(B_TOT, 3);
  ccb_kernel<<<g2, 256, 0, stream>>>(xds, conv_w, conv_b, bn_gamma, bn_beta,
                                     bn_mean, bn_var, bimap_w, ybuf);

  eig_kernel<<<B_TOT, 256, 0, stream>>>(ybuf, out);

  logits_kernel<<<NBS, 256, 0, stream>>>(out, linear_w, linear_b, out + FE_TOTAL);
}

// Round 3
// 1299.567 us; speedup vs baseline: 1.0482x; 1.0482x over previous
//
#include <hip/hip_runtime.h>

#define B_TOT 2304
#define CHAN 22
#define TP 250
#define KW 13
#define ST 64
#define RANK 32
#define FE_PER 528
#define FE_TOTAL (B_TOT * FE_PER)   // 1216512
#define FEAT 4752
#define NC 4
#define NBS 256

// ---------------- downsample: mean over groups of 4 ----------------
__global__ __launch_bounds__(256) void ds_kernel(const float* __restrict__ x,
                                                 float* __restrict__ xds, int n) {
  int idx = blockIdx.x * 256 + threadIdx.x;
  if (idx < n) {
    float4 v = reinterpret_cast<const float4*>(x)[idx];
    xds[idx] = (v.x + v.y + v.z + v.w) * 0.25f;
  }
}

// -------- conv + BN + center + P=W*S + y=P*P^T, one block per (b, m) --------
// y_m = (W S_c)(W S_c)^T / (3*ssq) + (1e-5/3) I,  ssq = ||S_c||_F^2
// (identical to (W C_norm W^T + 1e-5 I)/3 since trace(C)*(l-1) = ssq and W W^T = I)
__global__ __launch_bounds__(256) void ccb_kernel(
    const float* __restrict__ xds, const float* __restrict__ conv_w,
    const float* __restrict__ conv_b, const float* __restrict__ bn_gamma,
    const float* __restrict__ bn_beta, const float* __restrict__ bn_mean,
    const float* __restrict__ bn_var, const float* __restrict__ bimap_w,
    float* __restrict__ ybuf) {
  const int b = blockIdx.x;
  const int m = blockIdx.y;
  const int off = (m == 0) ? 0 : (m == 1) ? 84 : 167;
  const int l = (m == 0) ? 84 : 83;
  const int tid = threadIdx.x;

  __shared__ union UU {
    struct {
      float xseg[CHAN][96];      // input window [off-6, off+90)
      float wbuf[2][KW][ST];     // per-channel weight slice, transposed [k][o]
    } s1;
    float Wlds[RANK][65];        // bimap W (32x64, padded) after conv is done
  } u;
  __shared__ float S[ST][88];    // conv+bn output, then centered (even stride)
  __shared__ float P[RANK][86];  // P = W * S_c
  __shared__ float rowmean[ST];
  __shared__ float red4[4];

  // ---- stage input window ----
  const float* xb = xds + (size_t)b * CHAN * TP;
  for (int i = tid; i < CHAN * 96; i += 256) {
    int c = i / 96, tt = i - c * 96;
    int gt = off - 6 + tt;
    u.s1.xseg[c][tt] = (gt >= 0 && gt < TP) ? xb[c * TP + gt] : 0.0f;
  }
  // stage weights for c=0
  for (int j = tid; j < KW * ST; j += 256) {
    int k = j >> 6, o = j & 63;
    u.s1.wbuf[0][k][o] = conv_w[o * (CHAN * KW) + 0 * KW + k];
  }
  __syncthreads();

  // ---- conv + bias + BN -> S[o][t] ----
  {
    const int og = tid >> 4, tg = tid & 15;  // 16 o-groups x 16 t-groups
    const int o0 = og * 4, t0 = tg * 6;
    float acc[4][6];
#pragma unroll
    for (int a = 0; a < 4; a++)
#pragma unroll
      for (int t = 0; t < 6; t++) acc[a][t] = 0.f;

    for (int c = 0; c < CHAN; c++) {
      const int cur = c & 1;
      if (c + 1 < CHAN) {  // prefetch next channel's weights into other buffer
        for (int j = tid; j < KW * ST; j += 256) {
          int k = j >> 6, o = j & 63;
          u.s1.wbuf[cur ^ 1][k][o] = conv_w[o * (CHAN * KW) + (c + 1) * KW + k];
        }
      }
      if (t0 < l) {
        float win[18];
#pragma unroll
        for (int j = 0; j < 18; j += 2) {
          float2 w2 = *reinterpret_cast<float2*>(&u.s1.xseg[c][t0 + j]);
          win[j] = w2.x; win[j + 1] = w2.y;
        }
#pragma unroll
        for (int k = 0; k < KW; k++) {
          float4 wv = *reinterpret_cast<float4*>(&u.s1.wbuf[cur][k][o0]);
#pragma unroll
          for (int t = 0; t < 6; t++) {
            float xv = win[k + t];
            acc[0][t] += wv.x * xv;
            acc[1][t] += wv.y * xv;
            acc[2][t] += wv.z * xv;
            acc[3][t] += wv.w * xv;
          }
        }
      }
      __syncthreads();
    }

    if (t0 < l) {
#pragma unroll
      for (int a = 0; a < 4; a++) {
        int o = o0 + a;
        float inv = bn_gamma[o] * rsqrtf(bn_var[o] + 1e-5f);
        float shift = bn_beta[o] - bn_mean[o] * inv;
        float bias = conv_b[o];
#pragma unroll
        for (int t = 0; t < 6; t++) {
          int tt = t0 + t;
          if (tt < l) S[o][tt] = (acc[a][t] + bias) * inv + shift;
        }
      }
    }
  }
  __syncthreads();

  // ---- per-row mean over time ----
  {
    int row = tid >> 2, part = tid & 3;
    float ssum = 0.f;
    for (int t = part; t < l; t += 4) ssum += S[row][t];
    ssum += __shfl_xor(ssum, 1);
    ssum += __shfl_xor(ssum, 2);
    if (part == 0) rowmean[row] = ssum / (float)l;
  }
  __syncthreads();

  // ---- center + ssq; also stage W into LDS (union region now free) ----
  float ssq_loc = 0.f;
  for (int i = tid; i < ST * 84; i += 256) {
    int o = i / 84, t = i - o * 84;
    if (t < l) {
      float v = S[o][t] - rowmean[o];
      S[o][t] = v;
      ssq_loc += v * v;
    }
  }
  for (int j = tid; j < RANK * ST; j += 256) {
    u.Wlds[j >> 6][j & 63] = bimap_w[j];
  }
#pragma unroll
  for (int d = 32; d >= 1; d >>= 1) ssq_loc += __shfl_xor(ssq_loc, d);
  if ((tid & 63) == 0) red4[tid >> 6] = ssq_loc;
  __syncthreads();
  const float ssq = red4[0] + red4[1] + red4[2] + red4[3];

  // ---- P = W * S_c  (32 x l) ----
  {
    const int po = tid >> 4;        // 0..15 -> rows 2po, 2po+1
    const int ptg = tid & 15;       // t-chunk of 6
    const int t0p = ptg * 6;
    if (t0p < l) {
      float pacc[2][6];
#pragma unroll
      for (int a = 0; a < 2; a++)
#pragma unroll
        for (int t = 0; t < 6; t++) pacc[a][t] = 0.f;
      for (int i = 0; i < ST; i++) {
        float w0 = u.Wlds[2 * po][i];
        float w1 = u.Wlds[2 * po + 1][i];
        float sv[6];
#pragma unroll
        for (int j = 0; j < 6; j += 2) {
          float2 s2 = *reinterpret_cast<float2*>(&S[i][t0p + j]);
          sv[j] = s2.x; sv[j + 1] = s2.y;
        }
#pragma unroll
        for (int t = 0; t < 6; t++) {
          pacc[0][t] += w0 * sv[t];
          pacc[1][t] += w1 * sv[t];
        }
      }
#pragma unroll
      for (int a = 0; a < 2; a++)
#pragma unroll
        for (int t = 0; t < 6; t++) {
          int tt = t0p + t;
          if (tt < l) P[2 * po + a][tt] = pacc[a][t];
        }
    }
  }
  __syncthreads();

  // ---- y_m = P P^T / (3*ssq) + (1e-5/3) I -> ybuf ----
  {
    const int ty = tid >> 4;  // r0 = 2ty
    const int tx = tid & 15;  // c0 = 2tx
    const int r0 = 2 * ty, c0 = 2 * tx;
    float ya = 0.f, yb_ = 0.f, yc = 0.f, yd = 0.f;
    int t = 0;
    for (; t + 1 < l; t += 2) {
      float2 a0 = *reinterpret_cast<float2*>(&P[r0][t]);
      float2 a1 = *reinterpret_cast<float2*>(&P[r0 + 1][t]);
      float2 b0 = *reinterpret_cast<float2*>(&P[c0][t]);
      float2 b1 = *reinterpret_cast<float2*>(&P[c0 + 1][t]);
      ya += a0.x * b0.x + a0.y * b0.y;
      yb_ += a0.x * b1.x + a0.y * b1.y;
      yc += a1.x * b0.x + a1.y * b0.y;
      yd += a1.x * b1.x + a1.y * b1.y;
    }
    if (t < l) {
      float a0 = P[r0][t], a1 = P[r0 + 1][t], b0 = P[c0][t], b1 = P[c0 + 1][t];
      ya += a0 * b0; yb_ += a0 * b1; yc += a1 * b0; yd += a1 * b1;
    }
    const float sy = 1.0f / (3.0f * ssq);
    const float dg = 1e-5f / 3.0f;
    float* yp = ybuf + (size_t)(b * 3 + m) * RANK * RANK;
    yp[r0 * RANK + c0]           = ya * sy + ((r0 == c0) ? dg : 0.f);
    yp[r0 * RANK + c0 + 1]       = yb_ * sy;
    yp[(r0 + 1) * RANK + c0]     = yc * sy;
    yp[(r0 + 1) * RANK + c0 + 1] = yd * sy + ((r0 + 1 == c0 + 1) ? dg : 0.f);
  }
}

// -------- batched 32x32 symmetric eigh (cyclic Jacobi) + logm + fe --------
__global__ __launch_bounds__(256) void eig_kernel(const float* __restrict__ ybuf,
                                                  float* __restrict__ feout) {
  int b = blockIdx.x;
  int tid = threadIdx.x;
  __shared__ float A[32][33];
  __shared__ float V[32][33];
  __shared__ float cs[16], sn[16];
  __shared__ int pp[16], qq[16];
  __shared__ float lam[32];
  __shared__ float redo[4], redf[4];

  const float* yb = ybuf + (size_t)b * 3 * 1024;
  for (int i = tid; i < 1024; i += 256) {
    int r = i >> 5, c = i & 31;
    float v = yb[i] + yb[1024 + i] + yb[2048 + i];
    int it = c * 32 + r;
    float vt = yb[it] + yb[1024 + it] + yb[2048 + it];
    A[r][c] = 0.5f * (v + vt);
    V[r][c] = (r == c) ? 1.0f : 0.0f;
  }

  for (int sw = 0; sw < 12; sw++) {
    __syncthreads();
    // off-diagonal norm early exit
    float loc = 0.f, frol = 0.f;
    for (int i = tid; i < 1024; i += 256) {
      int r = i >> 5, c = i & 31;
      float v = A[r][c];
      frol += v * v;
      if (r != c) loc += v * v;
    }
#pragma unroll
    for (int d = 32; d >= 1; d >>= 1) {
      loc += __shfl_xor(loc, d);
      frol += __shfl_xor(frol, d);
    }
    if ((tid & 63) == 0) { redo[tid >> 6] = loc; redf[tid >> 6] = frol; }
    __syncthreads();
    float offn = redo[0] + redo[1] + redo[2] + redo[3];
    float fro2 = redf[0] + redf[1] + redf[2] + redf[3];
    if (offn <= 1e-13f * fro2) break;

    for (int rr = 0; rr < 31; rr++) {
      __syncthreads();
      if (tid < 16) {
        int p, q;
        if (tid == 0) { p = 31; q = rr; }
        else { p = (rr + tid) % 31; q = (rr + 31 - tid) % 31; }
        float app = A[p][p], aqq = A[q][q], apq = A[p][q];
        float c, s;
        if (fabsf(apq) < 1e-30f) { c = 1.f; s = 0.f; }
        else {
          float tau = (aqq - app) / (2.f * apq);
          float t = copysignf(1.f, tau) / (fabsf(tau) + sqrtf(1.f + tau * tau));
          c = rsqrtf(1.f + t * t);
          s = t * c;
        }
        cs[tid] = c; sn[tid] = s; pp[tid] = p; qq[tid] = q;
      }
      __syncthreads();
      // row phase: A <- J^T A
      for (int it = tid; it < 512; it += 256) {
        int k = it >> 5, col = it & 31;
        int p = pp[k], q = qq[k];
        float c = cs[k], s = sn[k];
        float ap = A[p][col], aq = A[q][col];
        A[p][col] = c * ap - s * aq;
        A[q][col] = s * ap + c * aq;
      }
      __syncthreads();
      // col phase: A <- A J,  V <- V J
      for (int it = tid; it < 1024; it += 256) {
        int k = (it >> 5) & 15;
        int row = it & 31;
        int p = pp[k], q = qq[k];
        float c = cs[k], s = sn[k];
        if (it < 512) {
          float ap = A[row][p], aq = A[row][q];
          A[row][p] = c * ap - s * aq;
          A[row][q] = s * ap + c * aq;
        } else {
          float vp = V[row][p], vq = V[row][q];
          V[row][p] = c * vp - s * vq;
          V[row][q] = s * vp + c * vq;
        }
      }
    }
  }
  __syncthreads();

  if (tid < 32) lam[tid] = logf(fmaxf(A[tid][tid], 1e-4f));
  __syncthreads();

  // fe = triu(V diag(lam) V^T) with sqrt(2) off-diag scaling
  for (int idx = tid; idx < FE_PER; idx += 256) {
    int i = 0, rem = idx;
    while (rem >= 32 - i) { rem -= 32 - i; i++; }
    int j = i + rem;
    float acc = 0.f;
#pragma unroll
    for (int k = 0; k < 32; k++) acc += V[i][k] * lam[k] * V[j][k];
    float scalef = (i == j) ? 1.0f : 1.4142135623730951f;
    feout[(size_t)b * FE_PER + idx] = acc * scalef;
  }
}

// ---------------- logits = fe @ W^T + b ----------------
__global__ __launch_bounds__(256) void logits_kernel(const float* __restrict__ fe,
                                                     const float* __restrict__ lw,
                                                     const float* __restrict__ lb,
                                                     float* __restrict__ outp) {
  int bs = blockIdx.x, tid = threadIdx.x;
  const float* f = fe + (size_t)bs * FEAT;
  float acc[NC] = {0.f, 0.f, 0.f, 0.f};
  for (int i = tid; i < FEAT; i += 256) {
    float v = f[i];
#pragma unroll
    for (int c = 0; c < NC; c++) acc[c] += v * lw[c * FEAT + i];
  }
  __shared__ float partial[4][NC];
#pragma unroll
  for (int c = 0; c < NC; c++) {
    float v = acc[c];
#pragma unroll
    for (int d = 32; d >= 1; d >>= 1) v += __shfl_xor(v, d);
    acc[c] = v;
  }
  if ((tid & 63) == 0) {
    int wave = tid >> 6;
#pragma unroll
    for (int c = 0; c < NC; c++) partial[wave][c] = acc[c];
  }
  __syncthreads();
  if (tid == 0) {
#pragma unroll
    for (int c = 0; c < NC; c++) {
      float sum = partial[0][c] + partial[1][c] + partial[2][c] + partial[3][c];
      outp[bs * NC + c] = sum + lb[c];
    }
  }
}

extern "C" void kernel_launch(void* const* d_in, const int* in_sizes, int n_in,
                              void* d_out, int out_size, void* d_ws, size_t ws_size,
                              hipStream_t stream) {
  const float* x        = (const float*)d_in[0];
  const float* conv_w   = (const float*)d_in[1];
  const float* conv_b   = (const float*)d_in[2];
  const float* bn_gamma = (const float*)d_in[3];
  const float* bn_beta  = (const float*)d_in[4];
  const float* bn_mean  = (const float*)d_in[5];
  const float* bn_var   = (const float*)d_in[6];
  const float* bimap_w  = (const float*)d_in[7];
  const float* linear_w = (const float*)d_in[8];
  const float* linear_b = (const float*)d_in[9];
  float* out = (float*)d_out;

  float* xds  = (float*)d_ws;          // 12,672,000 floats (50.7 MB)
  float* ybuf = xds + 12672000;        // 2304*3*1024 = 7,077,888 floats (28.3 MB)

  int n = B_TOT * CHAN * TP;
  ds_kernel<<<(n + 255) / 256, 256, 0, stream>>>(x, xds, n);

  dim3 g2(B_TOT, 3);
  ccb_kernel<<<g2, 256, 0, stream>>>(xds, conv_w, conv_b, bn_gamma, bn_beta,
                                     bn_mean, bn_var, bimap_w, ybuf);

  eig_kernel<<<B_TOT, 256, 0, stream>>>(ybuf, out);

  logits_kernel<<<NBS, 256, 0, stream>>>(out, linear_w, linear_b, out + FE_TOTAL);
}

// Round 4
// 1253.105 us; speedup vs baseline: 1.0871x; 1.0371x over previous
//
#include <hip/hip_runtime.h>

#define B_TOT 2304
#define CHAN 22
#define TP 250
#define KW 13
#define ST 64
#define RANK 32
#define FE_PER 528
#define FE_TOTAL (B_TOT * FE_PER)   // 1216512
#define FEAT 4752
#define NC 4
#define NBS 256
#define WTN (CHAN * KW * ST)        // 18304

// ---------------- downsample: mean over groups of 4 ----------------
__global__ __launch_bounds__(256) void ds_kernel(const float* __restrict__ x,
                                                 float* __restrict__ xds, int n) {
  int idx = blockIdx.x * 256 + threadIdx.x;
  if (idx < n) {
    float4 v = reinterpret_cast<const float4*>(x)[idx];
    xds[idx] = (v.x + v.y + v.z + v.w) * 0.25f;
  }
}

// ------- weight transpose + BN fold: wt[c][k][o] = conv_w[o][c][k]*inv[o] -------
__global__ __launch_bounds__(256) void wt_kernel(
    const float* __restrict__ conv_w, const float* __restrict__ conv_b,
    const float* __restrict__ bn_gamma, const float* __restrict__ bn_beta,
    const float* __restrict__ bn_mean, const float* __restrict__ bn_var,
    float* __restrict__ wt, float* __restrict__ bias_eff) {
  int idx = blockIdx.x * 256 + threadIdx.x;
  if (idx < WTN) {
    int c = idx / (KW * ST);
    int rem = idx - c * (KW * ST);
    int k = rem >> 6, o = rem & 63;
    float inv = bn_gamma[o] * rsqrtf(bn_var[o] + 1e-5f);
    wt[idx] = conv_w[o * (CHAN * KW) + c * KW + k] * inv;
  } else if (idx < WTN + ST) {
    int o = idx - WTN;
    float inv = bn_gamma[o] * rsqrtf(bn_var[o] + 1e-5f);
    bias_eff[o] = conv_b[o] * inv + bn_beta[o] - bn_mean[o] * inv;
  }
}

// -------- conv(+BN folded) + center + P=W*S + y=P*P^T, one block per (b, m) --------
// y_m = (W S_c)(W S_c)^T / (3*ssq) + (1e-5/3) I,  ssq = ||S_c||_F^2
__global__ __launch_bounds__(256) void ccb_kernel(
    const float* __restrict__ xds, const float* __restrict__ wt,
    const float* __restrict__ bias_eff, const float* __restrict__ bimap_w,
    float* __restrict__ ybuf) {
  const int b = blockIdx.x;
  const int m = blockIdx.y;
  const int off = (m == 0) ? 0 : (m == 1) ? 84 : 167;
  const int l = (m == 0) ? 84 : 83;
  const int tid = threadIdx.x;

  __shared__ union UU {
    struct {
      float xseg[CHAN][96];      // input window [off-6, off+90)
      float wbuf[2][KW * ST];    // per-channel BN-folded weights [k][o]
    } s1;
    float Wlds[RANK][65];        // bimap W after conv is done
  } u;
  __shared__ float S[ST][88];    // conv output, then centered
  __shared__ float P[RANK][86];  // P = W * S_c
  __shared__ float rowmean[ST];
  __shared__ float red4[4];

  // ---- stage input window + c=0 weights ----
  const float* xb = xds + (size_t)b * CHAN * TP;
  for (int i = tid; i < CHAN * 96; i += 256) {
    int c = i / 96, tt = i - c * 96;
    int gt = off - 6 + tt;
    u.s1.xseg[c][tt] = (gt >= 0 && gt < TP) ? xb[c * TP + gt] : 0.0f;
  }
  if (tid < 208) {
    float4 w4 = reinterpret_cast<const float4*>(wt)[tid];
    *reinterpret_cast<float4*>(&u.s1.wbuf[0][tid * 4]) = w4;
  }
  __syncthreads();

  // ---- conv -> S[o][t] ----
  {
    const int og = tid >> 4, tg = tid & 15;  // 16 o-groups x 16 t-groups
    const int o0 = og * 4, t0 = tg * 6;
    float acc[4][6];
#pragma unroll
    for (int a = 0; a < 4; a++)
#pragma unroll
      for (int t = 0; t < 6; t++) acc[a][t] = 0.f;

    for (int c = 0; c < CHAN; c++) {
      const int cur = c & 1;
      if (c + 1 < CHAN && tid < 208) {  // prefetch next channel (coalesced)
        float4 w4 = reinterpret_cast<const float4*>(wt + (size_t)(c + 1) * (KW * ST))[tid];
        *reinterpret_cast<float4*>(&u.s1.wbuf[cur ^ 1][tid * 4]) = w4;
      }
      if (t0 < l) {
        float win[18];
#pragma unroll
        for (int j = 0; j < 18; j += 2) {
          float2 w2 = *reinterpret_cast<float2*>(&u.s1.xseg[c][t0 + j]);
          win[j] = w2.x; win[j + 1] = w2.y;
        }
#pragma unroll
        for (int k = 0; k < KW; k++) {
          float4 wv = *reinterpret_cast<float4*>(&u.s1.wbuf[cur][k * 64 + o0]);
#pragma unroll
          for (int t = 0; t < 6; t++) {
            float xv = win[k + t];
            acc[0][t] += wv.x * xv;
            acc[1][t] += wv.y * xv;
            acc[2][t] += wv.z * xv;
            acc[3][t] += wv.w * xv;
          }
        }
      }
      __syncthreads();
    }

    if (t0 < l) {
#pragma unroll
      for (int a = 0; a < 4; a++) {
        int o = o0 + a;
        float be = bias_eff[o];
#pragma unroll
        for (int t = 0; t < 6; t++) {
          int tt = t0 + t;
          if (tt < l) S[o][tt] = acc[a][t] + be;
        }
      }
    }
  }
  __syncthreads();

  // ---- per-row mean over time ----
  {
    int row = tid >> 2, part = tid & 3;
    float ssum = 0.f;
    for (int t = part; t < l; t += 4) ssum += S[row][t];
    ssum += __shfl_xor(ssum, 1);
    ssum += __shfl_xor(ssum, 2);
    if (part == 0) rowmean[row] = ssum / (float)l;
  }
  __syncthreads();

  // ---- center + ssq; stage W into LDS (union region free now) ----
  float ssq_loc = 0.f;
  for (int i = tid; i < ST * 84; i += 256) {
    int o = i / 84, t = i - o * 84;
    if (t < l) {
      float v = S[o][t] - rowmean[o];
      S[o][t] = v;
      ssq_loc += v * v;
    }
  }
  for (int j = tid; j < RANK * ST; j += 256) {
    u.Wlds[j >> 6][j & 63] = bimap_w[j];
  }
#pragma unroll
  for (int d = 32; d >= 1; d >>= 1) ssq_loc += __shfl_xor(ssq_loc, d);
  if ((tid & 63) == 0) red4[tid >> 6] = ssq_loc;
  __syncthreads();
  const float ssq = red4[0] + red4[1] + red4[2] + red4[3];

  // ---- P = W * S_c  (32 x l) ----
  {
    const int po = tid >> 4;
    const int ptg = tid & 15;
    const int t0p = ptg * 6;
    if (t0p < l) {
      float pacc[2][6];
#pragma unroll
      for (int a = 0; a < 2; a++)
#pragma unroll
        for (int t = 0; t < 6; t++) pacc[a][t] = 0.f;
      for (int i = 0; i < ST; i++) {
        float w0 = u.Wlds[2 * po][i];
        float w1 = u.Wlds[2 * po + 1][i];
        float sv[6];
#pragma unroll
        for (int j = 0; j < 6; j += 2) {
          float2 s2 = *reinterpret_cast<float2*>(&S[i][t0p + j]);
          sv[j] = s2.x; sv[j + 1] = s2.y;
        }
#pragma unroll
        for (int t = 0; t < 6; t++) {
          pacc[0][t] += w0 * sv[t];
          pacc[1][t] += w1 * sv[t];
        }
      }
#pragma unroll
      for (int a = 0; a < 2; a++)
#pragma unroll
        for (int t = 0; t < 6; t++) {
          int tt = t0p + t;
          if (tt < l) P[2 * po + a][tt] = pacc[a][t];
        }
    }
  }
  __syncthreads();

  // ---- y_m = P P^T / (3*ssq) + (1e-5/3) I -> ybuf ----
  {
    const int ty = tid >> 4;
    const int tx = tid & 15;
    const int r0 = 2 * ty, c0 = 2 * tx;
    float ya = 0.f, yb_ = 0.f, yc = 0.f, yd = 0.f;
    int t = 0;
    for (; t + 1 < l; t += 2) {
      float2 a0 = *reinterpret_cast<float2*>(&P[r0][t]);
      float2 a1 = *reinterpret_cast<float2*>(&P[r0 + 1][t]);
      float2 b0 = *reinterpret_cast<float2*>(&P[c0][t]);
      float2 b1 = *reinterpret_cast<float2*>(&P[c0 + 1][t]);
      ya += a0.x * b0.x + a0.y * b0.y;
      yb_ += a0.x * b1.x + a0.y * b1.y;
      yc += a1.x * b0.x + a1.y * b0.y;
      yd += a1.x * b1.x + a1.y * b1.y;
    }
    if (t < l) {
      float a0 = P[r0][t], a1 = P[r0 + 1][t], b0 = P[c0][t], b1 = P[c0 + 1][t];
      ya += a0 * b0; yb_ += a0 * b1; yc += a1 * b0; yd += a1 * b1;
    }
    const float sy = 1.0f / (3.0f * ssq);
    const float dg = 1e-5f / 3.0f;
    float* yp = ybuf + (size_t)(b * 3 + m) * RANK * RANK;
    yp[r0 * RANK + c0]           = ya * sy + ((r0 == c0) ? dg : 0.f);
    yp[r0 * RANK + c0 + 1]       = yb_ * sy;
    yp[(r0 + 1) * RANK + c0]     = yc * sy;
    yp[(r0 + 1) * RANK + c0 + 1] = yd * sy + dg;
  }
}

// -------- 32x32 symmetric eigh: ONE WAVE per matrix (lockstep, no barriers) --------
__global__ __launch_bounds__(64) void eig_kernel(const float* __restrict__ ybuf,
                                                 float* __restrict__ feout) {
  const int b = blockIdx.x;
  const int lane = threadIdx.x;
  __shared__ float A[32][36];
  __shared__ float V[32][36];
  __shared__ float lam[32];

  const float* yb = ybuf + (size_t)b * 3072;
  for (int i = lane; i < 1024; i += 64) {
    int r = i >> 5, c = i & 31;
    float v = yb[i] + yb[1024 + i] + yb[2048 + i];
    int it = c * 32 + r;
    float vt = yb[it] + yb[1024 + it] + yb[2048 + it];
    A[r][c] = 0.5f * (v + vt);
    V[r][c] = (r == c) ? 1.0f : 0.0f;
  }
  __syncthreads();

  const int k = lane >> 2;      // pair index 0..15
  const int sub = lane & 3;     // column/row chunk 0..3
  const int c8 = 8 * sub;

  for (int sw = 0; sw < 12; sw++) {
    // off-diagonal norm, wave-local reduce
    float loc = 0.f, fro = 0.f;
    for (int i = lane; i < 1024; i += 64) {
      int r = i >> 5, c = i & 31;
      float v = A[r][c];
      fro += v * v;
      if (r != c) loc += v * v;
    }
#pragma unroll
    for (int d = 32; d >= 1; d >>= 1) {
      loc += __shfl_xor(loc, d);
      fro += __shfl_xor(fro, d);
    }
    if (loc <= 1e-13f * fro) break;

    for (int rr = 0; rr < 31; rr++) {
      int p, q;
      if (k == 0) { p = 31; q = rr; }
      else { p = (rr + k) % 31; q = (rr + 31 - k) % 31; }

      // rotation params (redundant within 4-lane group; LDS broadcast reads)
      float app = A[p][p], aqq = A[q][q], apq = A[p][q];
      bool tiny = fabsf(apq) < 1e-30f;
      float apq_s = tiny ? 1.0f : apq;
      float tau = (aqq - app) / (2.f * apq_s);
      float t = copysignf(1.f, tau) / (fabsf(tau) + sqrtf(1.f + tau * tau));
      float c_ = rsqrtf(1.f + t * t);
      float s_ = t * c_;
      c_ = tiny ? 1.f : c_;
      s_ = tiny ? 0.f : s_;

      // row phase: rows p,q; this lane handles cols c8..c8+7
      float4 rp0 = *reinterpret_cast<float4*>(&A[p][c8]);
      float4 rp1 = *reinterpret_cast<float4*>(&A[p][c8 + 4]);
      float4 rq0 = *reinterpret_cast<float4*>(&A[q][c8]);
      float4 rq1 = *reinterpret_cast<float4*>(&A[q][c8 + 4]);
      float4 np0, np1, nq0, nq1;
      np0.x = c_ * rp0.x - s_ * rq0.x;  nq0.x = s_ * rp0.x + c_ * rq0.x;
      np0.y = c_ * rp0.y - s_ * rq0.y;  nq0.y = s_ * rp0.y + c_ * rq0.y;
      np0.z = c_ * rp0.z - s_ * rq0.z;  nq0.z = s_ * rp0.z + c_ * rq0.z;
      np0.w = c_ * rp0.w - s_ * rq0.w;  nq0.w = s_ * rp0.w + c_ * rq0.w;
      np1.x = c_ * rp1.x - s_ * rq1.x;  nq1.x = s_ * rp1.x + c_ * rq1.x;
      np1.y = c_ * rp1.y - s_ * rq1.y;  nq1.y = s_ * rp1.y + c_ * rq1.y;
      np1.z = c_ * rp1.z - s_ * rq1.z;  nq1.z = s_ * rp1.z + c_ * rq1.z;
      np1.w = c_ * rp1.w - s_ * rq1.w;  nq1.w = s_ * rp1.w + c_ * rq1.w;
      *reinterpret_cast<float4*>(&A[p][c8])     = np0;
      *reinterpret_cast<float4*>(&A[p][c8 + 4]) = np1;
      *reinterpret_cast<float4*>(&A[q][c8])     = nq0;
      *reinterpret_cast<float4*>(&A[q][c8 + 4]) = nq1;
      __builtin_amdgcn_wave_barrier();

      // col phase: cols p,q of A and V; this lane handles rows c8..c8+7
#pragma unroll
      for (int j = 0; j < 8; j++) {
        int row = c8 + j;
        float ap = A[row][p], aq = A[row][q];
        A[row][p] = c_ * ap - s_ * aq;
        A[row][q] = s_ * ap + c_ * aq;
        float vp = V[row][p], vq = V[row][q];
        V[row][p] = c_ * vp - s_ * vq;
        V[row][q] = s_ * vp + c_ * vq;
      }
      __builtin_amdgcn_wave_barrier();
    }
  }
  __syncthreads();

  if (lane < 32) lam[lane] = logf(fmaxf(A[lane][lane], 1e-4f));
  __syncthreads();

  // A <- V * diag(lam)
  for (int i = lane; i < 1024; i += 64) {
    int r = i >> 5, c = i & 31;
    A[r][c] = V[r][c] * lam[c];
  }
  __syncthreads();

  // fe = triu(A V^T) with sqrt(2) off-diag scaling
  for (int idx = lane; idx < FE_PER; idx += 64) {
    int i = 0, rem = idx;
    while (rem >= 32 - i) { rem -= 32 - i; i++; }
    int j = i + rem;
    float acc = 0.f;
#pragma unroll
    for (int kk = 0; kk < 32; kk += 4) {
      float4 av = *reinterpret_cast<float4*>(&A[i][kk]);
      float4 vv = *reinterpret_cast<float4*>(&V[j][kk]);
      acc += av.x * vv.x + av.y * vv.y + av.z * vv.z + av.w * vv.w;
    }
    float scalef = (i == j) ? 1.0f : 1.4142135623730951f;
    feout[(size_t)b * FE_PER + idx] = acc * scalef;
  }
}

// ---------------- logits = fe @ W^T + b ----------------
__global__ __launch_bounds__(256) void logits_kernel(const float* __restrict__ fe,
                                                     const float* __restrict__ lw,
                                                     const float* __restrict__ lb,
                                                     float* __restrict__ outp) {
  int bs = blockIdx.x, tid = threadIdx.x;
  const float* f = fe + (size_t)bs * FEAT;
  float acc[NC] = {0.f, 0.f, 0.f, 0.f};
  for (int i = tid; i < FEAT; i += 256) {
    float v = f[i];
#pragma unroll
    for (int c = 0; c < NC; c++) acc[c] += v * lw[c * FEAT + i];
  }
  __shared__ float partial[4][NC];
#pragma unroll
  for (int c = 0; c < NC; c++) {
    float v = acc[c];
#pragma unroll
    for (int d = 32; d >= 1; d >>= 1) v += __shfl_xor(v, d);
    acc[c] = v;
  }
  if ((tid & 63) == 0) {
    int wave = tid >> 6;
#pragma unroll
    for (int c = 0; c < NC; c++) partial[wave][c] = acc[c];
  }
  __syncthreads();
  if (tid == 0) {
#pragma unroll
    for (int c = 0; c < NC; c++) {
      float sum = partial[0][c] + partial[1][c] + partial[2][c] + partial[3][c];
      outp[bs * NC + c] = sum + lb[c];
    }
  }
}

extern "C" void kernel_launch(void* const* d_in, const int* in_sizes, int n_in,
                              void* d_out, int out_size, void* d_ws, size_t ws_size,
                              hipStream_t stream) {
  const float* x        = (const float*)d_in[0];
  const float* conv_w   = (const float*)d_in[1];
  const float* conv_b   = (const float*)d_in[2];
  const float* bn_gamma = (const float*)d_in[3];
  const float* bn_beta  = (const float*)d_in[4];
  const float* bn_mean  = (const float*)d_in[5];
  const float* bn_var   = (const float*)d_in[6];
  const float* bimap_w  = (const float*)d_in[7];
  const float* linear_w = (const float*)d_in[8];
  const float* linear_b = (const float*)d_in[9];
  float* out = (float*)d_out;

  float* xds      = (float*)d_ws;            // 12,672,000 floats
  float* ybuf     = xds + 12672000;          // 7,077,888 floats
  float* wt       = ybuf + 7077888;          // 18,304 floats
  float* bias_eff = wt + WTN;                // 64 floats

  wt_kernel<<<(WTN + ST + 255) / 256, 256, 0, stream>>>(
      conv_w, conv_b, bn_gamma, bn_beta, bn_mean, bn_var, wt, bias_eff);

  int n = B_TOT * CHAN * TP;
  ds_kernel<<<(n + 255) / 256, 256, 0, stream>>>(x, xds, n);

  dim3 g2(B_TOT, 3);
  ccb_kernel<<<g2, 256, 0, stream>>>(xds, wt, bias_eff, bimap_w, ybuf);

  eig_kernel<<<B_TOT, 64, 0, stream>>>(ybuf, out);

  logits_kernel<<<NBS, 256, 0, stream>>>(out, linear_w, linear_b, out + FE_TOTAL);
}

// Round 5
// 1064.724 us; speedup vs baseline: 1.2794x; 1.1769x over previous
//
#include <hip/hip_runtime.h>

#define B_TOT 2304
#define CHAN 22
#define TP 250
#define KW 13
#define ST 64
#define RANK 32
#define FE_PER 528
#define FE_TOTAL (B_TOT * FE_PER)   // 1216512
#define FEAT 4752
#define NC 4
#define NBS 256
#define WTN (CHAN * KW * ST)        // 18304

// ---------------- downsample: mean over groups of 4 ----------------
__global__ __launch_bounds__(256) void ds_kernel(const float* __restrict__ x,
                                                 float* __restrict__ xds, int n) {
  int idx = blockIdx.x * 256 + threadIdx.x;
  if (idx < n) {
    float4 v = reinterpret_cast<const float4*>(x)[idx];
    xds[idx] = (v.x + v.y + v.z + v.w) * 0.25f;
  }
}

// ------- weight transpose + BN fold: wt[c][k][o] = conv_w[o][c][k]*inv[o] -------
__global__ __launch_bounds__(256) void wt_kernel(
    const float* __restrict__ conv_w, const float* __restrict__ conv_b,
    const float* __restrict__ bn_gamma, const float* __restrict__ bn_beta,
    const float* __restrict__ bn_mean, const float* __restrict__ bn_var,
    float* __restrict__ wt, float* __restrict__ bias_eff) {
  int idx = blockIdx.x * 256 + threadIdx.x;
  if (idx < WTN) {
    int c = idx / (KW * ST);
    int rem = idx - c * (KW * ST);
    int k = rem >> 6, o = rem & 63;
    float inv = bn_gamma[o] * rsqrtf(bn_var[o] + 1e-5f);
    wt[idx] = conv_w[o * (CHAN * KW) + c * KW + k] * inv;
  } else if (idx < WTN + ST) {
    int o = idx - WTN;
    float inv = bn_gamma[o] * rsqrtf(bn_var[o] + 1e-5f);
    bias_eff[o] = conv_b[o] * inv + bn_beta[o] - bn_mean[o] * inv;
  }
}

// -------- conv(+BN folded) + center + P=W*S + y=P*P^T, one block per (b, m) --------
// y_m = (W S_c)(W S_c)^T / (3*ssq) + (1e-5/3) I,  ssq = ||S_c||_F^2
__global__ __launch_bounds__(256) void ccb_kernel(
    const float* __restrict__ xds, const float* __restrict__ wt,
    const float* __restrict__ bias_eff, const float* __restrict__ bimap_w,
    float* __restrict__ ybuf) {
  const int b = blockIdx.x;
  const int m = blockIdx.y;
  const int off = (m == 0) ? 0 : (m == 1) ? 84 : 167;
  const int l = (m == 0) ? 84 : 83;
  const int tid = threadIdx.x;

  __shared__ union UU {
    struct {
      float xseg[CHAN][96];      // input window [off-6, off+90)
      float wbuf[2][KW * ST];    // per-channel BN-folded weights [k][o]
    } s1;
    float Wlds[RANK][65];        // bimap W after conv is done
  } u;
  __shared__ float S[ST][88];    // conv output, then centered
  __shared__ float P[RANK][86];  // P = W * S_c
  __shared__ float rowmean[ST];
  __shared__ float red4[4];

  // ---- stage input window + c=0 weights ----
  const float* xb = xds + (size_t)b * CHAN * TP;
  for (int i = tid; i < CHAN * 96; i += 256) {
    int c = i / 96, tt = i - c * 96;
    int gt = off - 6 + tt;
    u.s1.xseg[c][tt] = (gt >= 0 && gt < TP) ? xb[c * TP + gt] : 0.0f;
  }
  if (tid < 208) {
    float4 w4 = reinterpret_cast<const float4*>(wt)[tid];
    *reinterpret_cast<float4*>(&u.s1.wbuf[0][tid * 4]) = w4;
  }
  __syncthreads();

  // ---- conv -> S[o][t]; o-tile 2, t-tile 12 (og=tid>>3, tg=tid&7) ----
  {
    const int og = tid >> 3;       // 0..31 -> o0 = 2*og
    const int tg = tid & 7;        // 0..7 -> t0 = 12*tg, active tg<7
    const int o0 = og * 2, t0 = tg * 12;
    const bool act = (tg < 7);
    float acc[2][12];
#pragma unroll
    for (int a = 0; a < 2; a++)
#pragma unroll
      for (int t = 0; t < 12; t++) acc[a][t] = 0.f;

    for (int c = 0; c < CHAN; c++) {
      const int cur = c & 1;
      if (c + 1 < CHAN && tid < 208) {  // prefetch next channel (coalesced)
        float4 w4 = reinterpret_cast<const float4*>(wt + (size_t)(c + 1) * (KW * ST))[tid];
        *reinterpret_cast<float4*>(&u.s1.wbuf[cur ^ 1][tid * 4]) = w4;
      }
      if (act) {
        float win[24];
#pragma unroll
        for (int j = 0; j < 24; j += 2) {
          float2 w2 = *reinterpret_cast<float2*>(&u.s1.xseg[c][t0 + j]);
          win[j] = w2.x; win[j + 1] = w2.y;
        }
#pragma unroll
        for (int k = 0; k < KW; k++) {
          float2 wv = *reinterpret_cast<float2*>(&u.s1.wbuf[cur][k * 64 + o0]);
#pragma unroll
          for (int t = 0; t < 12; t++) {
            float xv = win[k + t];
            acc[0][t] += wv.x * xv;
            acc[1][t] += wv.y * xv;
          }
        }
      }
      __syncthreads();
    }

    if (act) {
      float be0 = bias_eff[o0], be1 = bias_eff[o0 + 1];
#pragma unroll
      for (int t = 0; t < 12; t++) {
        int tt = t0 + t;
        if (tt < l) {
          S[o0][tt]     = acc[0][t] + be0;
          S[o0 + 1][tt] = acc[1][t] + be1;
        }
      }
    }
  }
  __syncthreads();

  // ---- per-row mean over time ----
  {
    int row = tid >> 2, part = tid & 3;
    float ssum = 0.f;
    for (int t = part; t < l; t += 4) ssum += S[row][t];
    ssum += __shfl_xor(ssum, 1);
    ssum += __shfl_xor(ssum, 2);
    if (part == 0) rowmean[row] = ssum / (float)l;
  }
  __syncthreads();

  // ---- center + ssq; stage W into LDS (union region free now) ----
  float ssq_loc = 0.f;
  for (int i = tid; i < ST * 84; i += 256) {
    int o = i / 84, t = i - o * 84;
    if (t < l) {
      float v = S[o][t] - rowmean[o];
      S[o][t] = v;
      ssq_loc += v * v;
    }
  }
  for (int j = tid; j < RANK * ST; j += 256) {
    u.Wlds[j >> 6][j & 63] = bimap_w[j];
  }
#pragma unroll
  for (int d = 32; d >= 1; d >>= 1) ssq_loc += __shfl_xor(ssq_loc, d);
  if ((tid & 63) == 0) red4[tid >> 6] = ssq_loc;
  __syncthreads();
  const float ssq = red4[0] + red4[1] + red4[2] + red4[3];

  // ---- P = W * S_c  (32 x l) ----
  {
    const int po = tid >> 4;
    const int ptg = tid & 15;
    const int t0p = ptg * 6;
    if (t0p < l) {
      float pacc[2][6];
#pragma unroll
      for (int a = 0; a < 2; a++)
#pragma unroll
        for (int t = 0; t < 6; t++) pacc[a][t] = 0.f;
      for (int i = 0; i < ST; i++) {
        float w0 = u.Wlds[2 * po][i];
        float w1 = u.Wlds[2 * po + 1][i];
        float sv[6];
#pragma unroll
        for (int j = 0; j < 6; j += 2) {
          float2 s2 = *reinterpret_cast<float2*>(&S[i][t0p + j]);
          sv[j] = s2.x; sv[j + 1] = s2.y;
        }
#pragma unroll
        for (int t = 0; t < 6; t++) {
          pacc[0][t] += w0 * sv[t];
          pacc[1][t] += w1 * sv[t];
        }
      }
#pragma unroll
      for (int a = 0; a < 2; a++)
#pragma unroll
        for (int t = 0; t < 6; t++) {
          int tt = t0p + t;
          if (tt < l) P[2 * po + a][tt] = pacc[a][t];
        }
    }
  }
  __syncthreads();

  // ---- y_m = P P^T / (3*ssq) + (1e-5/3) I -> ybuf ----
  {
    const int ty = tid >> 4;
    const int tx = tid & 15;
    const int r0 = 2 * ty, c0 = 2 * tx;
    float ya = 0.f, yb_ = 0.f, yc = 0.f, yd = 0.f;
    int t = 0;
    for (; t + 1 < l; t += 2) {
      float2 a0 = *reinterpret_cast<float2*>(&P[r0][t]);
      float2 a1 = *reinterpret_cast<float2*>(&P[r0 + 1][t]);
      float2 b0 = *reinterpret_cast<float2*>(&P[c0][t]);
      float2 b1 = *reinterpret_cast<float2*>(&P[c0 + 1][t]);
      ya += a0.x * b0.x + a0.y * b0.y;
      yb_ += a0.x * b1.x + a0.y * b1.y;
      yc += a1.x * b0.x + a1.y * b0.y;
      yd += a1.x * b1.x + a1.y * b1.y;
    }
    if (t < l) {
      float a0 = P[r0][t], a1 = P[r0 + 1][t], b0 = P[c0][t], b1 = P[c0 + 1][t];
      ya += a0 * b0; yb_ += a0 * b1; yc += a1 * b0; yd += a1 * b1;
    }
    const float sy = 1.0f / (3.0f * ssq);
    const float dg = 1e-5f / 3.0f;
    float* yp = ybuf + (size_t)(b * 3 + m) * RANK * RANK;
    yp[r0 * RANK + c0]           = ya * sy + ((r0 == c0) ? dg : 0.f);
    yp[r0 * RANK + c0 + 1]       = yb_ * sy;
    yp[(r0 + 1) * RANK + c0]     = yc * sy;
    yp[(r0 + 1) * RANK + c0 + 1] = yd * sy + dg;
  }
}

// -------- 32x32 symmetric eigh: ONE WAVE per matrix (lockstep, no barriers) --------
__global__ __launch_bounds__(64) void eig_kernel(const float* __restrict__ ybuf,
                                                 float* __restrict__ feout) {
  const int b = blockIdx.x;
  const int lane = threadIdx.x;
  __shared__ float A[32][36];
  __shared__ float V[32][36];
  __shared__ float lam[32];

  const float* yb = ybuf + (size_t)b * 3072;
  for (int i = lane; i < 1024; i += 64) {
    int r = i >> 5, c = i & 31;
    float v = yb[i] + yb[1024 + i] + yb[2048 + i];
    int it = c * 32 + r;
    float vt = yb[it] + yb[1024 + it] + yb[2048 + it];
    A[r][c] = 0.5f * (v + vt);
    V[r][c] = (r == c) ? 1.0f : 0.0f;
  }
  __syncthreads();

  const int k = lane >> 2;      // pair index 0..15
  const int sub = lane & 3;     // chunk 0..3
  const int c8 = 8 * sub;

  for (int sw = 0; sw < 12; sw++) {
    // off-diagonal norm, wave-local reduce
    float loc = 0.f, fro = 0.f;
    for (int i = lane; i < 1024; i += 64) {
      int r = i >> 5, c = i & 31;
      float v = A[r][c];
      fro += v * v;
      if (r != c) loc += v * v;
    }
#pragma unroll
    for (int d = 32; d >= 1; d >>= 1) {
      loc += __shfl_xor(loc, d);
      fro += __shfl_xor(fro, d);
    }
    if (loc <= 1e-13f * fro) break;

    for (int rr = 0; rr < 31; rr++) {
      int p, q;
      if (k == 0) { p = 31; q = rr; }
      else { p = (rr + k) % 31; q = (rr + 31 - k) % 31; }

      // rotation params (redundant within 4-lane group; LDS broadcast reads)
      float app = A[p][p], aqq = A[q][q], apq = A[p][q];
      bool tiny = fabsf(apq) < 1e-30f;
      float apq_s = tiny ? 1.0f : apq;
      float tau = (aqq - app) / (2.f * apq_s);
      float t = copysignf(1.f, tau) / (fabsf(tau) + sqrtf(1.f + tau * tau));
      float c_ = rsqrtf(1.f + t * t);
      float s_ = t * c_;
      c_ = tiny ? 1.f : c_;
      s_ = tiny ? 0.f : s_;

      // row phase: rows p,q; this lane handles cols c8..c8+7
      float4 rp0 = *reinterpret_cast<float4*>(&A[p][c8]);
      float4 rp1 = *reinterpret_cast<float4*>(&A[p][c8 + 4]);
      float4 rq0 = *reinterpret_cast<float4*>(&A[q][c8]);
      float4 rq1 = *reinterpret_cast<float4*>(&A[q][c8 + 4]);
      float4 np0, np1, nq0, nq1;
      np0.x = c_ * rp0.x - s_ * rq0.x;  nq0.x = s_ * rp0.x + c_ * rq0.x;
      np0.y = c_ * rp0.y - s_ * rq0.y;  nq0.y = s_ * rp0.y + c_ * rq0.y;
      np0.z = c_ * rp0.z - s_ * rq0.z;  nq0.z = s_ * rp0.z + c_ * rq0.z;
      np0.w = c_ * rp0.w - s_ * rq0.w;  nq0.w = s_ * rp0.w + c_ * rq0.w;
      np1.x = c_ * rp1.x - s_ * rq1.x;  nq1.x = s_ * rp1.x + c_ * rq1.x;
      np1.y = c_ * rp1.y - s_ * rq1.y;  nq1.y = s_ * rp1.y + c_ * rq1.y;
      np1.z = c_ * rp1.z - s_ * rq1.z;  nq1.z = s_ * rp1.z + c_ * rq1.z;
      np1.w = c_ * rp1.w - s_ * rq1.w;  nq1.w = s_ * rp1.w + c_ * rq1.w;
      *reinterpret_cast<float4*>(&A[p][c8])     = np0;
      *reinterpret_cast<float4*>(&A[p][c8 + 4]) = np1;
      *reinterpret_cast<float4*>(&A[q][c8])     = nq0;
      *reinterpret_cast<float4*>(&A[q][c8 + 4]) = nq1;
      __builtin_amdgcn_wave_barrier();

      // col phase: cols p,q of A and V; lane handles rows 4j+sub (bank-spread)
#pragma unroll
      for (int j = 0; j < 8; j++) {
        int row = 4 * j + sub;
        float ap = A[row][p], aq = A[row][q];
        A[row][p] = c_ * ap - s_ * aq;
        A[row][q] = s_ * ap + c_ * aq;
        float vp = V[row][p], vq = V[row][q];
        V[row][p] = c_ * vp - s_ * vq;
        V[row][q] = s_ * vp + c_ * vq;
      }
      __builtin_amdgcn_wave_barrier();
    }
  }
  __syncthreads();

  if (lane < 32) lam[lane] = logf(fmaxf(A[lane][lane], 1e-4f));
  __syncthreads();

  // A <- V * diag(lam)
  for (int i = lane; i < 1024; i += 64) {
    int r = i >> 5, c = i & 31;
    A[r][c] = V[r][c] * lam[c];
  }
  __syncthreads();

  // fe = triu(A V^T) with sqrt(2) off-diag scaling
  for (int idx = lane; idx < FE_PER; idx += 64) {
    int i = 0, rem = idx;
    while (rem >= 32 - i) { rem -= 32 - i; i++; }
    int j = i + rem;
    float acc = 0.f;
#pragma unroll
    for (int kk = 0; kk < 32; kk += 4) {
      float4 av = *reinterpret_cast<float4*>(&A[i][kk]);
      float4 vv = *reinterpret_cast<float4*>(&V[j][kk]);
      acc += av.x * vv.x + av.y * vv.y + av.z * vv.z + av.w * vv.w;
    }
    float scalef = (i == j) ? 1.0f : 1.4142135623730951f;
    feout[(size_t)b * FE_PER + idx] = acc * scalef;
  }
}

// ---------------- logits = fe @ W^T + b ----------------
__global__ __launch_bounds__(256) void logits_kernel(const float* __restrict__ fe,
                                                     const float* __restrict__ lw,
                                                     const float* __restrict__ lb,
                                                     float* __restrict__ outp) {
  int bs = blockIdx.x, tid = threadIdx.x;
  const float* f = fe + (size_t)bs * FEAT;
  float acc[NC] = {0.f, 0.f, 0.f, 0.f};
  for (int i = tid; i < FEAT; i += 256) {
    float v = f[i];
#pragma unroll
    for (int c = 0; c < NC; c++) acc[c] += v * lw[c * FEAT + i];
  }
  __shared__ float partial[4][NC];
#pragma unroll
  for (int c = 0; c < NC; c++) {
    float v = acc[c];
#pragma unroll
    for (int d = 32; d >= 1; d >>= 1) v += __shfl_xor(v, d);
    acc[c] = v;
  }
  if ((tid & 63) == 0) {
    int wave = tid >> 6;
#pragma unroll
    for (int c = 0; c < NC; c++) partial[wave][c] = acc[c];
  }
  __syncthreads();
  if (tid == 0) {
#pragma unroll
    for (int c = 0; c < NC; c++) {
      float sum = partial[0][c] + partial[1][c] + partial[2][c] + partial[3][c];
      outp[bs * NC + c] = sum + lb[c];
    }
  }
}

extern "C" void kernel_launch(void* const* d_in, const int* in_sizes, int n_in,
                              void* d_out, int out_size, void* d_ws, size_t ws_size,
                              hipStream_t stream) {
  const float* x        = (const float*)d_in[0];
  const float* conv_w   = (const float*)d_in[1];
  const float* conv_b   = (const float*)d_in[2];
  const float* bn_gamma = (const float*)d_in[3];
  const float* bn_beta  = (const float*)d_in[4];
  const float* bn_mean  = (const float*)d_in[5];
  const float* bn_var   = (const float*)d_in[6];
  const float* bimap_w  = (const float*)d_in[7];
  const float* linear_w = (const float*)d_in[8];
  const float* linear_b = (const float*)d_in[9];
  float* out = (float*)d_out;

  float* xds      = (float*)d_ws;            // 12,672,000 floats
  float* ybuf     = xds + 12672000;          // 7,077,888 floats
  float* wt       = ybuf + 7077888;          // 18,304 floats
  float* bias_eff = wt + WTN;                // 64 floats

  wt_kernel<<<(WTN + ST + 255) / 256, 256, 0, stream>>>(
      conv_w, conv_b, bn_gamma, bn_beta, bn_mean, bn_var, wt, bias_eff);

  int n = B_TOT * CHAN * TP;
  ds_kernel<<<(n + 255) / 256, 256, 0, stream>>>(x, xds, n);

  dim3 g2(B_TOT, 3);
  ccb_kernel<<<g2, 256, 0, stream>>>(xds, wt, bias_eff, bimap_w, ybuf);

  eig_kernel<<<B_TOT, 64, 0, stream>>>(ybuf, out);

  logits_kernel<<<NBS, 256, 0, stream>>>(out, linear_w, linear_b, out + FE_TOTAL);
}